// Round 23
// baseline (179.222 us; speedup 1.0000x reference)
//
#include <hip/hip_runtime.h>
#include <hip/hip_bf16.h>

#define BATCH 16
#define SEQ   2048
#define HD    128
#define QBLK  64
#define KVBLK 64
#define NT    (SEQ / KVBLK)   // 32 iterations
#define NW    4

typedef __attribute__((ext_vector_type(8))) short bf16x8;
typedef __attribute__((ext_vector_type(4))) float f32x4;
typedef __attribute__((ext_vector_type(4))) short s16x4;

__device__ __forceinline__ short f2bf(float x) {
    __hip_bfloat16 h = __float2bfloat16(x);
    return *reinterpret_cast<short*>(&h);
}

// r18 lean loop (111.3us best: no-max softmax, rcp-hoist, setprio, 1 barrier)
// with KVBLK=64: ISF read granule 128B->256B (theory: DRAM-efficiency-bound on
// the 268MB ISF stream at 128B scattered granules -> ~2.6 of 6.3 TB/s),
// barriers halved, K-tile read amplification halved.
// LDS: Klds dbuf 32KB + Vt dbuf (stride 70: banks 3d%32, conflict-free) 35KB
// + private P pads 9KB = 77.8KB -> 2 blocks/CU.
__global__ __launch_bounds__(256, 2)
void attn_fused(const float* __restrict__ Q, const float* __restrict__ K,
                const float* __restrict__ V, const float* __restrict__ ISF,
                float* __restrict__ O)
{
    const int tid  = threadIdx.x;
    const int lane = tid & 63;
    const int wv   = tid >> 6;      // wave 0..3, owns q-rows [wv*16, wv*16+16)
    const int lg   = lane >> 4;     // 16-lane group 0..3
    const int lc   = lane & 15;

    const int bidx = blockIdx.x;
    const int b    = bidx >> 5;            // 32 q-tiles per batch
    const int q0   = (bidx & 31) * QBLK;

    __shared__ short Klds[2][64 * 128];    // XOR-swizzled 16B chunks (32KB)
    __shared__ short Vtlds[2][128 * 70];   // transposed V [d][kv], stride 70 (35KB)
    __shared__ short Plds[NW * 16 * 72];   // per-wave 16x64 P tile, stride 72 (9KB)

    // ---- hoist Q fragments (A operand): row = q0 + wv*16 + lc, k = ks*32 + lg*8 + j ----
    bf16x8 qf[4];
    {
        const float* qrow = Q + ((size_t)b * SEQ + q0 + wv * 16 + lc) * HD;
        #pragma unroll
        for (int ks = 0; ks < 4; ++ks) {
            const float* p = qrow + ks * 32 + lg * 8;
            float4 x0 = *reinterpret_cast<const float4*>(p);
            float4 x1 = *reinterpret_cast<const float4*>(p + 4);
            bf16x8 f;
            f[0]=f2bf(x0.x); f[1]=f2bf(x0.y); f[2]=f2bf(x0.z); f[3]=f2bf(x0.w);
            f[4]=f2bf(x1.x); f[5]=f2bf(x1.y); f[6]=f2bf(x1.z); f[7]=f2bf(x1.w);
            qf[ks] = f;
        }
    }

    f32x4 oacc[8];
    #pragma unroll
    for (int i = 0; i < 8; ++i) oacc[i] = (f32x4){0.f, 0.f, 0.f, 0.f};
    float l_part[4] = {0.f, 0.f, 0.f, 0.f};   // per-lane partial row sums

    const float* kbase = K + (size_t)b * SEQ * HD;
    const float* vbase = V + (size_t)b * SEQ * HD;
    const float* ibase = ISF + ((size_t)b * SEQ + q0 + wv * 16) * SEQ;

    float4 kreg[8];
    float  vreg[8][4];
    float  isf_cur[16], isf_nxt[16];  // isf_cur holds rcp(isf)*log2e

    auto LOAD = [&](int kv0) {
        const float* kb = kbase + (size_t)kv0 * HD;
        const float* vb = vbase + (size_t)kv0 * HD;
        #pragma unroll
        for (int r = 0; r < 8; ++r) {
            int idx = r * 256 + tid;
            kreg[r] = *reinterpret_cast<const float4*>(kb + (size_t)(idx >> 5) * HD + (idx & 31) * 4);
        }
        #pragma unroll
        for (int r = 0; r < 8; ++r) {
            int idx = r * 256 + tid;
            int d = idx & 127, kq = idx >> 7;       // kq 0..15
            #pragma unroll
            for (int j = 0; j < 4; ++j)
                vreg[r][j] = vb[(size_t)(kq * 4 + j) * HD + d];
        }
    };
    auto LOAD_ISF = [&](int kv0, float* dst) {
        #pragma unroll
        for (int nt = 0; nt < 4; ++nt)
            #pragma unroll
            for (int r = 0; r < 4; ++r)
                dst[nt * 4 + r] = ibase[(size_t)(lg * 4 + r) * SEQ + kv0 + nt * 16 + lc];
    };
    auto STORE = [&](int buf) {
        #pragma unroll
        for (int r = 0; r < 8; ++r) {
            int idx = r * 256 + tid;
            int kvr = idx >> 5, d4 = idx & 31;
            s16x4 s;
            s[0]=f2bf(kreg[r].x); s[1]=f2bf(kreg[r].y); s[2]=f2bf(kreg[r].z); s[3]=f2bf(kreg[r].w);
            int chunk = (d4 >> 1) ^ (kvr & 7);
            *reinterpret_cast<s16x4*>(&Klds[buf][kvr * 128 + chunk * 8 + (d4 & 1) * 4]) = s;
        }
        #pragma unroll
        for (int r = 0; r < 8; ++r) {
            int idx = r * 256 + tid;
            int d = idx & 127, kq = idx >> 7;
            s16x4 s;
            #pragma unroll
            for (int j = 0; j < 4; ++j) s[j] = f2bf(vreg[r][j]);
            *reinterpret_cast<s16x4*>(&Vtlds[buf][d * 70 + kq * 4]) = s;
        }
    };

    // ---- prologue: tile 0 into buf 0 ----
    LOAD(0);
    LOAD_ISF(0, isf_nxt);
    STORE(0);
    __syncthreads();
    #pragma unroll
    for (int i = 0; i < 16; ++i)
        isf_cur[i] = __builtin_amdgcn_rcpf(isf_nxt[i]) * 1.44269504f;

    int cur = 0;
    for (int t = 0; t < NT; ++t) {
        const int kv0n = (t + 1) * KVBLK;
        const bool more = (t + 1 < NT);
        if (more) { LOAD(kv0n); LOAD_ISF(kv0n, isf_nxt); }   // in flight under compute

        // ---- S = Q·K^T (16 rows x 64 cols per wave) ----
        f32x4 sacc[4];
        #pragma unroll
        for (int nt = 0; nt < 4; ++nt) sacc[nt] = (f32x4){0.f,0.f,0.f,0.f};
        __builtin_amdgcn_s_setprio(1);
        #pragma unroll
        for (int nt = 0; nt < 4; ++nt) {
            int n = lc + nt * 16;
            #pragma unroll
            for (int ks = 0; ks < 4; ++ks) {
                int chunk = (ks * 4 + lg) ^ (n & 7);
                bf16x8 bf = *reinterpret_cast<const bf16x8*>(&Klds[cur][n * 128 + chunk * 8]);
                sacc[nt] = __builtin_amdgcn_mfma_f32_16x16x32_bf16(qf[ks], bf, sacc[nt], 0, 0, 0);
            }
        }
        __builtin_amdgcn_s_setprio(0);

        // ---- P = exp2(qk * rcp(isf)*log2e), unnormalized ----
        short pb[4][4];
        #pragma unroll
        for (int nt = 0; nt < 4; ++nt)
            #pragma unroll
            for (int r = 0; r < 4; ++r) {
                float p = __builtin_amdgcn_exp2f(sacc[nt][r] * isf_cur[nt * 4 + r]);
                l_part[r] += p;
                pb[nt][r] = f2bf(p);
            }

        // ---- P: D-layout -> A-frag layout via per-wave LDS tile (stride 72) ----
        short* pw = &Plds[wv * 16 * 72];
        #pragma unroll
        for (int nt = 0; nt < 4; ++nt)
            #pragma unroll
            for (int r = 0; r < 4; ++r)
                pw[(lg * 4 + r) * 72 + nt * 16 + lc] = pb[nt][r];
        bf16x8 pa0 = *reinterpret_cast<const bf16x8*>(&pw[lc * 72 + lg * 8]);
        bf16x8 pa1 = *reinterpret_cast<const bf16x8*>(&pw[lc * 72 + 32 + lg * 8]);

        // ---- O += P·V (two k-halves) ----
        __builtin_amdgcn_s_setprio(1);
        #pragma unroll
        for (int dt = 0; dt < 8; ++dt) {
            const short* vrow = &Vtlds[cur][(lc + dt * 16) * 70];
            bf16x8 vf0 = *reinterpret_cast<const bf16x8*>(&vrow[lg * 8]);
            bf16x8 vf1 = *reinterpret_cast<const bf16x8*>(&vrow[32 + lg * 8]);
            oacc[dt] = __builtin_amdgcn_mfma_f32_16x16x32_bf16(pa0, vf0, oacc[dt], 0, 0, 0);
            oacc[dt] = __builtin_amdgcn_mfma_f32_16x16x32_bf16(pa1, vf1, oacc[dt], 0, 0, 0);
        }
        __builtin_amdgcn_s_setprio(0);

        // ---- land tile t+1 in the other buffers; single barrier per iter ----
        if (more) STORE(cur ^ 1);
        __syncthreads();
        cur ^= 1;
        #pragma unroll
        for (int i = 0; i < 16; ++i)
            isf_cur[i] = __builtin_amdgcn_rcpf(isf_nxt[i]) * 1.44269504f;
    }

    // ---- epilogue: one-time row-sum reduce (16-lane butterfly), normalize, store ----
    #pragma unroll
    for (int msk = 1; msk < 16; msk <<= 1)
        #pragma unroll
        for (int r = 0; r < 4; ++r)
            l_part[r] += __shfl_xor(l_part[r], msk, 64);

    float* ob = O + ((size_t)b * SEQ + q0 + wv * 16) * HD;
    #pragma unroll
    for (int r = 0; r < 4; ++r) {
        float inv_l = 1.0f / l_part[r];
        float* orow = ob + (size_t)(lg * 4 + r) * HD;
        #pragma unroll
        for (int dt = 0; dt < 8; ++dt)
            orow[lc + dt * 16] = oacc[dt][r] * inv_l;
    }
}

extern "C" void kernel_launch(void* const* d_in, const int* in_sizes, int n_in,
                              void* d_out, int out_size, void* d_ws, size_t ws_size,
                              hipStream_t stream) {
    const float* q   = (const float*)d_in[0];
    const float* k   = (const float*)d_in[1];
    const float* v   = (const float*)d_in[2];
    const float* isf = (const float*)d_in[3];
    float* out = (float*)d_out;
    dim3 grid(BATCH * (SEQ / QBLK));   // 512 blocks
    attn_fused<<<grid, 256, 0, stream>>>(q, k, v, isf, out);
}

// Round 24
// 108.932 us; speedup vs baseline: 1.6453x; 1.6453x over previous
//
#include <hip/hip_runtime.h>
#include <hip/hip_bf16.h>

#define BATCH 16
#define SEQ   2048
#define HD    128
#define QBLK  64
#define KVBLK 32
#define NT    (SEQ / KVBLK)
#define NW    4

typedef __attribute__((ext_vector_type(8))) short bf16x8;
typedef __attribute__((ext_vector_type(4))) float f32x4;
typedef __attribute__((ext_vector_type(4))) short s16x4;

__device__ __forceinline__ short f2bf(float x) {
    __hip_bfloat16 h = __float2bfloat16(x);
    return *reinterpret_cast<short*>(&h);
}

// r18 (111.3us best) + block-parity KV phase stagger:
// the 2 co-resident blocks/CU run [load->compute->barrier] in lockstep
// (launched together, barriers re-sync) -> both hit the same pipe then both
// stall together (all pipes <25%). Odd blocks start the KV loop at tile NT/2
// and wrap -- commutative no-max softmax makes order irrelevant -- so the two
// blocks' memory/compute phases de-correlate and fill each other's gaps.
__global__ __launch_bounds__(256, 2)
void attn_fused(const float* __restrict__ Q, const float* __restrict__ K,
                const float* __restrict__ V, const float* __restrict__ ISF,
                float* __restrict__ O)
{
    const int tid  = threadIdx.x;
    const int lane = tid & 63;
    const int wv   = tid >> 6;      // wave 0..3, owns q-rows [wv*16, wv*16+16)
    const int lg   = lane >> 4;     // 16-lane group 0..3
    const int lc   = lane & 15;

    const int bidx = blockIdx.x;
    const int b    = bidx >> 5;            // 32 q-tiles per batch
    const int q0   = (bidx & 31) * QBLK;
    const int tofs = (bidx & 1) * (NT / 2);   // phase stagger: odd blocks start mid-sequence

    __shared__ short Klds[2][32 * 128];    // XOR-swizzled 16B chunks
    __shared__ short Vtlds[2][128 * 40];   // transposed V [d][kv], stride 40 shorts
    __shared__ short Plds[NW * 16 * 40];

    // ---- hoist Q fragments (A operand): row = q0 + wv*16 + lc, k = ks*32 + lg*8 + j ----
    bf16x8 qf[4];
    {
        const float* qrow = Q + ((size_t)b * SEQ + q0 + wv * 16 + lc) * HD;
        #pragma unroll
        for (int ks = 0; ks < 4; ++ks) {
            const float* p = qrow + ks * 32 + lg * 8;
            float4 x0 = *reinterpret_cast<const float4*>(p);
            float4 x1 = *reinterpret_cast<const float4*>(p + 4);
            bf16x8 f;
            f[0]=f2bf(x0.x); f[1]=f2bf(x0.y); f[2]=f2bf(x0.z); f[3]=f2bf(x0.w);
            f[4]=f2bf(x1.x); f[5]=f2bf(x1.y); f[6]=f2bf(x1.z); f[7]=f2bf(x1.w);
            qf[ks] = f;
        }
    }

    f32x4 oacc[8];
    #pragma unroll
    for (int i = 0; i < 8; ++i) oacc[i] = (f32x4){0.f, 0.f, 0.f, 0.f};
    float l_part[4] = {0.f, 0.f, 0.f, 0.f};   // per-lane partial row sums

    const float* kbase = K + (size_t)b * SEQ * HD;
    const float* vbase = V + (size_t)b * SEQ * HD;
    const float* ibase = ISF + ((size_t)b * SEQ + q0 + wv * 16) * SEQ;

    float4 kreg[4];
    float  vreg[4][4];
    float  isf_cur[8], isf_nxt[8];  // isf_cur holds rcp(isf)*log2e

    auto LOAD = [&](int kv0) {
        const float* kb = kbase + (size_t)kv0 * HD;
        const float* vb = vbase + (size_t)kv0 * HD;
        #pragma unroll
        for (int r = 0; r < 4; ++r) {
            int idx = r * 256 + tid;
            kreg[r] = *reinterpret_cast<const float4*>(kb + (size_t)(idx >> 5) * HD + (idx & 31) * 4);
        }
        #pragma unroll
        for (int r = 0; r < 4; ++r) {
            int idx = r * 256 + tid;
            int d = idx & 127, kq = idx >> 7;
            #pragma unroll
            for (int j = 0; j < 4; ++j)
                vreg[r][j] = vb[(size_t)(kq * 4 + j) * HD + d];
        }
    };
    auto LOAD_ISF = [&](int kv0, float* dst) {
        #pragma unroll
        for (int nt = 0; nt < 2; ++nt)
            #pragma unroll
            for (int r = 0; r < 4; ++r)
                dst[nt * 4 + r] = ibase[(size_t)(lg * 4 + r) * SEQ + kv0 + nt * 16 + lc];
    };
    auto STORE = [&](int buf) {
        #pragma unroll
        for (int r = 0; r < 4; ++r) {
            int idx = r * 256 + tid;
            int kvr = idx >> 5, d4 = idx & 31;
            s16x4 s;
            s[0]=f2bf(kreg[r].x); s[1]=f2bf(kreg[r].y); s[2]=f2bf(kreg[r].z); s[3]=f2bf(kreg[r].w);
            int chunk = (d4 >> 1) ^ (kvr & 7);
            *reinterpret_cast<s16x4*>(&Klds[buf][kvr * 128 + chunk * 8 + (d4 & 1) * 4]) = s;
        }
        #pragma unroll
        for (int r = 0; r < 4; ++r) {
            int idx = r * 256 + tid;
            int d = idx & 127, kq = idx >> 7;
            s16x4 s;
            #pragma unroll
            for (int j = 0; j < 4; ++j) s[j] = f2bf(vreg[r][j]);
            *reinterpret_cast<s16x4*>(&Vtlds[buf][d * 40 + kq * 4]) = s;
        }
    };

    // staggered tile sequence: t_eff = (t + tofs) & (NT-1)
    auto KV0 = [&](int t) { return (((t + tofs) & (NT - 1)) * KVBLK); };

    // ---- prologue: first tile of this block's sequence into buf 0 ----
    LOAD(KV0(0));
    LOAD_ISF(KV0(0), isf_nxt);
    STORE(0);
    __syncthreads();
    #pragma unroll
    for (int i = 0; i < 8; ++i)
        isf_cur[i] = __builtin_amdgcn_rcpf(isf_nxt[i]) * 1.44269504f;

    int cur = 0;
    for (int t = 0; t < NT; ++t) {
        const bool more = (t + 1 < NT);
        if (more) { LOAD(KV0(t + 1)); LOAD_ISF(KV0(t + 1), isf_nxt); }   // in flight under compute

        // ---- S = Q·K^T (16 rows x 32 cols per wave) ----
        f32x4 sacc[2];
        sacc[0] = (f32x4){0.f,0.f,0.f,0.f};
        sacc[1] = (f32x4){0.f,0.f,0.f,0.f};
        __builtin_amdgcn_s_setprio(1);
        #pragma unroll
        for (int nt = 0; nt < 2; ++nt) {
            int n = lc + nt * 16;
            #pragma unroll
            for (int ks = 0; ks < 4; ++ks) {
                int chunk = (ks * 4 + lg) ^ (n & 7);
                bf16x8 bf = *reinterpret_cast<const bf16x8*>(&Klds[cur][n * 128 + chunk * 8]);
                sacc[nt] = __builtin_amdgcn_mfma_f32_16x16x32_bf16(qf[ks], bf, sacc[nt], 0, 0, 0);
            }
        }
        __builtin_amdgcn_s_setprio(0);

        // ---- P = exp2(qk * rcp(isf)*log2e), unnormalized (|score| <= ~9) ----
        short pb[2][4];
        #pragma unroll
        for (int nt = 0; nt < 2; ++nt)
            #pragma unroll
            for (int r = 0; r < 4; ++r) {
                float p = __builtin_amdgcn_exp2f(sacc[nt][r] * isf_cur[nt * 4 + r]);
                l_part[r] += p;
                pb[nt][r] = f2bf(p);
            }

        // ---- P: D-layout -> A-frag layout via per-wave LDS tile ----
        short* pw = &Plds[wv * 16 * 40];
        #pragma unroll
        for (int nt = 0; nt < 2; ++nt)
            #pragma unroll
            for (int r = 0; r < 4; ++r)
                pw[(lg * 4 + r) * 40 + nt * 16 + lc] = pb[nt][r];
        bf16x8 pa = *reinterpret_cast<const bf16x8*>(&pw[lc * 40 + lg * 8]);

        // ---- O += P·V ----
        __builtin_amdgcn_s_setprio(1);
        #pragma unroll
        for (int dt = 0; dt < 8; ++dt) {
            bf16x8 vf = *reinterpret_cast<const bf16x8*>(&Vtlds[cur][(lc + dt * 16) * 40 + lg * 8]);
            oacc[dt] = __builtin_amdgcn_mfma_f32_16x16x32_bf16(pa, vf, oacc[dt], 0, 0, 0);
        }
        __builtin_amdgcn_s_setprio(0);

        // ---- land tile t+1 in the other buffer; single barrier per iter ----
        if (more) STORE(cur ^ 1);
        __syncthreads();
        cur ^= 1;
        #pragma unroll
        for (int i = 0; i < 8; ++i)
            isf_cur[i] = __builtin_amdgcn_rcpf(isf_nxt[i]) * 1.44269504f;
    }

    // ---- epilogue: one-time row-sum reduce (16-lane butterfly), normalize, store ----
    #pragma unroll
    for (int msk = 1; msk < 16; msk <<= 1)
        #pragma unroll
        for (int r = 0; r < 4; ++r)
            l_part[r] += __shfl_xor(l_part[r], msk, 64);

    float* ob = O + ((size_t)b * SEQ + q0 + wv * 16) * HD;
    #pragma unroll
    for (int r = 0; r < 4; ++r) {
        float inv_l = 1.0f / l_part[r];
        float* orow = ob + (size_t)(lg * 4 + r) * HD;
        #pragma unroll
        for (int dt = 0; dt < 8; ++dt)
            orow[lc + dt * 16] = oacc[dt][r] * inv_l;
    }
}

extern "C" void kernel_launch(void* const* d_in, const int* in_sizes, int n_in,
                              void* d_out, int out_size, void* d_ws, size_t ws_size,
                              hipStream_t stream) {
    const float* q   = (const float*)d_in[0];
    const float* k   = (const float*)d_in[1];
    const float* v   = (const float*)d_in[2];
    const float* isf = (const float*)d_in[3];
    float* out = (float*)d_out;
    dim3 grid(BATCH * (SEQ / QBLK));   // 512 blocks
    attn_fused<<<grid, 256, 0, stream>>>(q, k, v, isf, out);
}